// Round 11
// baseline (2646.438 us; speedup 1.0000x reference)
//
#include <hip/hip_runtime.h>
#include <math.h>

#define B_ 8
#define T_ 1000
#define C_ 8
#define F_ 257
#define A_ 320
#define TSLICE_ 10
#define TRANGE_ 100   // t per block
#define CHT_ 20       // t per chunk
#define NCHK_ 5

// ---------------- Kernel 1: FUSED transpose+PSD ---------------------------------
// Block = (ts, ftile, b): 16 f's x 100 t's. x staged straight from (B,T,C,F)
// layout (coalesced 64B c-rows) into LDS float2 [20][8][17]; masks streamed
// per-thread as contiguous float4 (1-ahead pipeline). Thread (fl,c,h) owns
// 4 e's x 2 masks. Partial sums per t-slice; combined downstream.
__global__ __launch_bounds__(256) void k_psdf(
    const float* __restrict__ dre, const float* __restrict__ dim_,
    const float* __restrict__ ms, const float* __restrict__ mn,
    float2* __restrict__ psp, float2* __restrict__ pnp,
    float* __restrict__ msum, float* __restrict__ nsum) {
  __shared__ float2 xl[CHT_][C_][17];   // 21760 B (pad 17 -> <=2-way banks)
  int ts = blockIdx.x;        // 0..9
  int f0 = blockIdx.y * 16;   // 0..16 tiles
  int b  = blockIdx.z;
  int tid = threadIdx.x;
  int fl = tid & 15;
  int c  = (tid >> 4) & 7;
  int h  = tid >> 7;          // 0/1 -> e in {0..3} / {4..7}
  int t00 = ts * TRANGE_;

  int fme = f0 + fl; if (fme > 256) fme = 256;   // clamp (read-dup, write-skip)
  const float4* mr4 = (const float4*)(ms + (((size_t)b * F_ + fme) * C_ + c) * T_ + t00);
  const float4* nr4 = (const float4*)(mn + (((size_t)b * F_ + fme) * C_ + c) * T_ + t00);

  size_t grow = ((size_t)b * T_ + t00) * (C_ * F_) + (size_t)c * F_ + fme;

  float xsR[10], xsI[10];

  // prologue: stage chunk 0 (thread stages its own (fl,c) at t = h + 2p)
#pragma unroll
  for (int p = 0; p < 10; ++p) {
    size_t ga = grow + (size_t)(h + 2 * p) * (C_ * F_);
    xsR[p] = dre[ga]; xsI[p] = dim_[ga];
  }
  float4 msA = mr4[0], mnA = nr4[0];
  float4 msB = msA, mnB = mnA;
#pragma unroll
  for (int p = 0; p < 10; ++p) xl[h + 2 * p][c][fl] = make_float2(xsR[p], xsI[p]);
  asm volatile("s_waitcnt lgkmcnt(0)" ::: "memory");
  __builtin_amdgcn_s_barrier();

  float asR[4] = {0,0,0,0}, asI[4] = {0,0,0,0};
  float anR[4] = {0,0,0,0}, anI[4] = {0,0,0,0};
  float ss = 0.f, sn = 0.f;

#pragma unroll
  for (int ch = 0; ch < NCHK_; ++ch) {
    // issue next chunk's x loads early (full chunk of compute as cover)
    if (ch < NCHK_ - 1) {
      size_t gb = grow + (size_t)((ch + 1) * CHT_) * (C_ * F_);
#pragma unroll
      for (int p = 0; p < 10; ++p) {
        size_t ga = gb + (size_t)(h + 2 * p) * (C_ * F_);
        xsR[p] = dre[ga]; xsI[p] = dim_[ga];
      }
    }
    // compute chunk (masks pipelined 1 float4 ahead; contiguous stream -> L1)
#pragma unroll
    for (int j4 = 0; j4 < 5; ++j4) {
      int nidx = ch * 5 + j4 + 1;
      if (nidx < 25) { msB = mr4[nidx]; mnB = nr4[nidx]; }
#pragma unroll
      for (int jj = 0; jj < 4; ++jj) {
        int tt = j4 * 4 + jj;
        float m = (jj == 0) ? msA.x : (jj == 1) ? msA.y : (jj == 2) ? msA.z : msA.w;
        float n = (jj == 0) ? mnA.x : (jj == 1) ? mnA.y : (jj == 2) ? mnA.z : mnA.w;
        float2 xc = xl[tt][c][fl];
        ss += m; sn += n;
        float ysx = m * xc.x, ysy = m * xc.y;
        float ynx = n * xc.x, yny = n * xc.y;
#pragma unroll
        for (int je = 0; je < 4; ++je) {
          float2 xe = xl[tt][h * 4 + je][fl];
          asR[je] += ysx * xe.x + ysy * xe.y;   // m*(x_c conj(x_e)).re
          asI[je] += ysy * xe.x - ysx * xe.y;   // .im
          anR[je] += ynx * xe.x + yny * xe.y;
          anI[je] += yny * xe.x - ynx * xe.y;
        }
      }
      msA = msB; mnA = mnB;
    }
    __builtin_amdgcn_s_barrier();       // all reads of this chunk retired
    if (ch < NCHK_ - 1) {
#pragma unroll
      for (int p = 0; p < 10; ++p) xl[h + 2 * p][c][fl] = make_float2(xsR[p], xsI[p]);
      asm volatile("s_waitcnt lgkmcnt(0)" ::: "memory");   // lgkm only: x/mask
      __builtin_amdgcn_s_barrier();                        // loads stay in flight
    }
  }

  if (f0 + fl < F_) {
    size_t obase = (((size_t)b * F_ + f0 + fl) * TSLICE_ + ts) * 64 + c * 8 + h * 4;
#pragma unroll
    for (int je = 0; je < 4; ++je) {
      psp[obase + je] = make_float2(asR[je], asI[je]);
      pnp[obase + je] = make_float2(anR[je], anI[je]);
    }
    if (h == 0) {
      size_t mbase = (((size_t)b * F_ + f0 + fl) * TSLICE_ + ts) * 8 + c;
      msum[mbase] = ss; nsum[mbase] = sn;
    }
  }
}

// ---------------- Kernel 2b: combine slices -> attention features ---------------
__global__ __launch_bounds__(64) void k_comb(
    const float2* __restrict__ psp, const float* __restrict__ msum,
    float* __restrict__ feat) {
  int bf = blockIdx.x;
  int b = bf / F_;
  int f = bf - b * F_;
  int l = threadIdx.x;
  int c = l >> 3, e = l & 7;

  float sr_ = 0.f, si_ = 0.f, ssum = 0.f;
#pragma unroll
  for (int hh = 0; hh < TSLICE_; ++hh) {
    float2 s = psp[((size_t)bf * TSLICE_ + hh) * 64 + l];
    sr_ += s.x; si_ += s.y;
    ssum += msum[((size_t)bf * TSLICE_ + hh) * 8 + c];
  }
  float inv = 1.f / (ssum + 1e-6f);
  float fr = (e == c) ? 0.f : sr_ * inv;
  float fi = (e == c) ? 0.f : si_ * inv;
#pragma unroll
  for (int s = 4; s >= 1; s >>= 1) { fr += __shfl_xor(fr, s); fi += __shfl_xor(fi, s); }
  if (e == 0) {
    fr *= (1.f / 7.f); fi *= (1.f / 7.f);
    feat[(b * C_ + c) * F_ + f] = sqrtf(fr * fr + fi * fi);
  }
}

// ---------------- Kernel 3: attention MLP partial logits ----------------------
__global__ __launch_bounds__(64) void k_attn(
    const float* __restrict__ feat, const float* __restrict__ wmlp,
    const float* __restrict__ bmlp, const float* __restrict__ wgv,
    float* __restrict__ e_part) {
  __shared__ float fl[C_ * F_];   // 8224 B
  int b = blockIdx.x, p = blockIdx.y;
  int tid = threadIdx.x;
  for (int i = tid; i < C_ * F_; i += 64) fl[i] = feat[b * C_ * F_ + i];
  __syncthreads();

  int a = p * 64 + tid;           // A = 320 = 5*64
  const float* wr = wmlp + a * F_;
  float acc[C_];
  float bm = bmlp[a];
#pragma unroll
  for (int c = 0; c < C_; ++c) acc[c] = bm;
  for (int k = 0; k < F_; ++k) {
    float w = wr[k];
#pragma unroll
    for (int c = 0; c < C_; ++c) acc[c] += w * fl[c * F_ + k];
  }
  float wg = wgv[a];
  float ec[C_];
#pragma unroll
  for (int c = 0; c < C_; ++c) ec[c] = wg * tanhf(acc[c]);

#pragma unroll
  for (int s = 32; s >= 1; s >>= 1) {
#pragma unroll
    for (int c = 0; c < C_; ++c) ec[c] += __shfl_xor(ec[c], s);
  }
  if (tid == 0) {
#pragma unroll
    for (int c = 0; c < C_; ++c) e_part[(b * 5 + p) * C_ + c] = ec[c];
  }
}

// ---------------- Kernel 4: softmax + combine + tik-reg + solve + ws -----------
__global__ __launch_bounds__(64) void k_solve(
    const float2* __restrict__ psp, const float2* __restrict__ pnp,
    const float* __restrict__ msum, const float* __restrict__ nsum,
    const float* __restrict__ e_part, float2* __restrict__ wsv) {
  int bf = blockIdx.x;
  int b = bf / F_;
  int l = threadIdx.x;
  int r = l >> 3, q = l & 7;

  // softmax over channels
  float e_c = 0.f;
#pragma unroll
  for (int p = 0; p < 5; ++p) e_c += e_part[(b * 5 + p) * C_ + q];
  e_c *= 2.0f;  // SCALING
  float mx = e_c;
#pragma unroll
  for (int s = 4; s >= 1; s >>= 1) mx = fmaxf(mx, __shfl_xor(mx, s));
  float ex = expf(e_c - mx);
  float sm = ex;
#pragma unroll
  for (int s = 4; s >= 1; s >>= 1) sm += __shfl_xor(sm, s);
  float uq = ex / sm;

  // combine slices + per-row mask normalization
  float Mx = 0.f, My = 0.f, Rx = 0.f, Ry = 0.f, nsr = 0.f, msr = 0.f;
#pragma unroll
  for (int hh = 0; hh < TSLICE_; ++hh) {
    float2 m_ = pnp[((size_t)bf * TSLICE_ + hh) * 64 + l];
    float2 r_ = psp[((size_t)bf * TSLICE_ + hh) * 64 + l];
    Mx += m_.x; My += m_.y; Rx += r_.x; Ry += r_.y;
    nsr += nsum[((size_t)bf * TSLICE_ + hh) * 8 + r];
    msr += msum[((size_t)bf * TSLICE_ + hh) * 8 + r];
  }
  float invn = 1.f / (nsr + 1e-6f);
  float invm = 1.f / (msr + 1e-6f);
  float2 M = make_float2(Mx * invn, My * invn);
  float2 R = make_float2(Rx * invm, Ry * invm);

  // trace(psd_n).real
  float td = (r == q) ? M.x : 0.f;
#pragma unroll
  for (int s = 32; s >= 1; s >>= 1) td += __shfl_xor(td, s);
  if (r == q) M.x += 1e-7f * (td * 0.125f) + 1e-8f;

  // Gauss-Jordan: M X = R  ->  R becomes X
#pragma unroll
  for (int k = 0; k < 8; ++k) {
    float pr = __shfl(M.x, k * 9), pi = __shfl(M.y, k * 9);
    float den = pr * pr + pi * pi;
    float ir = pr / den, ii = -pi / den;          // 1/pivot
    float mkr = __shfl(M.x, k * 8 + q), mki = __shfl(M.y, k * 8 + q);
    float rkr = __shfl(R.x, k * 8 + q), rki = __shfl(R.y, k * 8 + q);
    float gr = __shfl(M.x, r * 8 + k), gi = __shfl(M.y, r * 8 + k);
    if (r == k) {
      float nmr = M.x * ir - M.y * ii, nmi = M.x * ii + M.y * ir;
      float nrr = R.x * ir - R.y * ii, nri = R.x * ii + R.y * ir;
      M = make_float2(nmr, nmi); R = make_float2(nrr, nri);
    } else {
      float fr = gr * ir - gi * ii, fi = gr * ii + gi * ir;   // M[r,k]/pivot
      M.x -= fr * mkr - fi * mki; M.y -= fr * mki + fi * mkr;
      R.x -= fr * rkr - fi * rki; R.y -= fr * rki + fi * rkr;
    }
  }

  // trace(X), normalize, apply u
  float trr = (r == q) ? R.x : 0.f, tri = (r == q) ? R.y : 0.f;
#pragma unroll
  for (int s = 32; s >= 1; s >>= 1) { trr += __shfl_xor(trr, s); tri += __shfl_xor(tri, s); }
  trr += 1e-6f;  // + EPS
  float den = trr * trr + tri * tri;
  float ir = trr / den, ii = -tri / den;
  float wr_ = R.x * ir - R.y * ii;   // ws_mat[r][q]
  float wi_ = R.x * ii + R.y * ir;
  float vr = wr_ * uq, vi = wi_ * uq;
#pragma unroll
  for (int s = 4; s >= 1; s >>= 1) { vr += __shfl_xor(vr, s); vi += __shfl_xor(vi, s); }
  if (q == 0) wsv[(size_t)bf * C_ + r] = make_float2(vr, vi);
}

// ---------------- Kernel 5: enhanced[b,t,f] = sum_c conj(ws) * x ----------------
__global__ __launch_bounds__(256) void k_bf(
    const float* __restrict__ dre, const float* __restrict__ dim_,
    const float2* __restrict__ wsv, float2* __restrict__ out) {
  __shared__ float2 wl[C_][F_];
  int blk = blockIdx.x;
  int b = blk / 125;
  int t0 = (blk - b * 125) * 8;
  int tid = threadIdx.x;
  for (int i = tid; i < C_ * F_; i += 256) {
    int f = i >> 3, c = i & 7;
    wl[c][f] = wsv[(size_t)b * (F_ * C_) + i];
  }
  __syncthreads();

  for (int dt = 0; dt < 8; ++dt) {
    int t = t0 + dt;
    const float* pr = dre + (size_t)(b * T_ + t) * (C_ * F_);
    const float* pi_ = dim_ + (size_t)(b * T_ + t) * (C_ * F_);
    for (int f = tid; f < F_; f += 256) {
      float ar = 0.f, ai = 0.f;
#pragma unroll
      for (int c = 0; c < C_; ++c) {
        float xr = pr[c * F_ + f], xi = pi_[c * F_ + f];
        float2 w = wl[c][f];
        ar += w.x * xr + w.y * xi;   // conj(w)*x
        ai += w.x * xi - w.y * xr;
      }
      out[(size_t)(b * T_ + t) * F_ + f] = make_float2(ar, ai);
    }
  }
}

extern "C" void kernel_launch(void* const* d_in, const int* in_sizes, int n_in,
                              void* d_out, int out_size, void* d_ws, size_t ws_size,
                              hipStream_t stream) {
  const float* dre = (const float*)d_in[0];
  const float* dim_ = (const float*)d_in[1];
  const float* ms = (const float*)d_in[2];
  const float* mn = (const float*)d_in[3];
  const float* wmlp = (const float*)d_in[4];
  const float* bmlp = (const float*)d_in[5];
  const float* wgv = (const float*)d_in[6];
  // d_in[7] = b_gvec: cancels in softmax — unused.

  char* ws = (char*)d_ws;
  float2* psp  = (float2*)(ws);                 // 2056*10*64*8 = 10,526,720 B
  float2* pnp  = (float2*)(ws + 10526720);      // 10,526,720 B
  float*  msum = (float*) (ws + 21053440);      // 2056*10*8*4 = 657,920 B
  float*  nsum = (float*) (ws + 21711360);      // 657,920 B
  float*  feat = (float*) (ws + 22369280);      // 65,792 B
  float*  e_prt= (float*) (ws + 22435072);      // 1,280 B
  float2* wsv  = (float2*)(ws + 22436352);      // 131,584 B  (end ~22.6 MB)

  dim3 gp(TSLICE_, 17, B_);
  k_psdf<<<gp, 256, 0, stream>>>(dre, dim_, ms, mn, psp, pnp, msum, nsum);
  k_comb<<<B_ * F_, 64, 0, stream>>>(psp, msum, feat);
  dim3 ga(B_, 5, 1);
  k_attn<<<ga, 64, 0, stream>>>(feat, wmlp, bmlp, wgv, e_prt);
  k_solve<<<B_ * F_, 64, 0, stream>>>(psp, pnp, msum, nsum, e_prt, wsv);
  k_bf<<<B_ * 125, 256, 0, stream>>>(dre, dim_, wsv, (float2*)d_out);
}